// Round 2
// baseline (16009.633 us; speedup 1.0000x reference)
//
#include <hip/hip_runtime.h>
#include <math.h>

// B=32, D=256, T=1024, H=512, 4H=2048
// ws layout: [0, 16MB) xT bf16 [T][B][D]; +16MB barrier (256B); then hbuf fp32 [2][32][512]
// ws required: ~16.9 MB

using short8 = __attribute__((ext_vector_type(8))) short;   // 8 bf16
using f32x4  = __attribute__((ext_vector_type(4))) float;

__device__ inline unsigned short f2bf(float f) {
    unsigned u = __float_as_uint(f);
    unsigned r = u + 0x7fffu + ((u >> 16) & 1u);
    return (unsigned short)(r >> 16);
}

__global__ void zero_barrier(unsigned* p) {
    p[threadIdx.x] = 0u;
}

// ---------------- Phase 1: xT[t][b][d] = bf16(x[b][d][t]) ----------------
__global__ __launch_bounds__(256) void x_transpose(const float* __restrict__ x,
                                                   unsigned short* __restrict__ xT) {
    __shared__ unsigned short tile[64][65];
    const int tid = threadIdx.x;
    const int t0 = blockIdx.x * 64, d0 = blockIdx.y * 64, b = blockIdx.z;
    // read: coalesced along t
    for (int p = 0; p < 16; p++) {
        int d = p * 4 + (tid >> 6);
        int t = tid & 63;
        tile[d][t] = f2bf(x[(b * 256 + d0 + d) * 1024 + t0 + t]);
    }
    __syncthreads();
    // write: coalesced along d
    for (int p = 0; p < 16; p++) {
        int t = p * 4 + (tid >> 6);
        int d = tid & 63;
        xT[(size_t)(t0 + t) * 8192 + b * 256 + d0 + d] = tile[d][t];
    }
}

// ---------------- Phase 2: persistent recurrence, 32 blocks x 512 threads ----------------
// block g owns h indices [16g, 16g+16) for all 32 batches.
// wave w = (gate = w>>1, mt = w&1): computes 16(batch)x16(n) tile, n = gate*512 + g*16 + l15
#define NBLK 32
#define HLDS_STRIDE 520   // shorts, 1040 B (16B-mult, 4-bank rotation -> 2-way, free)
#define XLDS_STRIDE 264   // shorts, 528 B

__global__ __launch_bounds__(512) void lstm_rec(const unsigned short* __restrict__ xT,
                                                const float* __restrict__ Wih,
                                                const float* __restrict__ Whh,
                                                const float* __restrict__ bih,
                                                const float* __restrict__ bhh,
                                                float* __restrict__ out,
                                                unsigned* barrier_buf,
                                                float* hbuf) {
    __shared__ __align__(16) unsigned short h_lds[32 * HLDS_STRIDE];  // 33.3 KB
    __shared__ __align__(16) unsigned short x_lds[32 * XLDS_STRIDE];  // 16.9 KB
    __shared__ float gates_lds[4 * 32 * 16];                          // 8 KB

    const int tid  = threadIdx.x;
    const int wave = tid >> 6;         // 0..7
    const int lane = tid & 63;
    const int quad = lane >> 4, l15 = lane & 15;
    const int g    = blockIdx.x;
    const int gate = wave >> 1;        // i,f,g,o
    const int mt   = wave & 1;         // batch half

    const int nrow = gate * 512 + g * 16 + l15;   // W row / gate index for this lane's column

    // preload B-frags into registers (one-time, uncoalesced is fine)
    short8 whh_frag[16];
    for (int ks = 0; ks < 16; ks++) {
        const float* p = &Whh[(size_t)nrow * 512 + ks * 32 + quad * 8];
        short8 v;
        for (int j = 0; j < 8; j++) v[j] = (short)f2bf(p[j]);
        whh_frag[ks] = v;
    }
    short8 wih_frag[8];
    for (int ks = 0; ks < 8; ks++) {
        const float* p = &Wih[(size_t)nrow * 256 + ks * 32 + quad * 8];
        short8 v;
        for (int j = 0; j < 8; j++) v[j] = (short)f2bf(p[j]);
        wih_frag[ks] = v;
    }
    const float bias_n = bih[nrow] + bhh[nrow];

    // zero h_lds; stage x_lds for t=0
    for (int i = tid; i < 32 * HLDS_STRIDE; i += 512) h_lds[i] = 0;
    {
        const unsigned short* src = xT + tid * 16;    // t = 0
        int b = tid >> 4, d = (tid & 15) * 16;
        *(short8*)&x_lds[b * XLDS_STRIDE + d]     = *(const short8*)src;
        *(short8*)&x_lds[b * XLDS_STRIDE + d + 8] = *(const short8*)(src + 8);
    }

    const int eb = tid >> 4, ek = tid & 15;       // elementwise ownership: (batch, local k)
    const int hidx = g * 16 + ek;
    float c = 0.0f;
    float* out_base = out + ((size_t)eb * 512 + hidx) * 1024;

    unsigned* cnt = barrier_buf;
    unsigned* gen = barrier_buf + 32;

    __syncthreads();

    for (int t = 0; t < 1024; t++) {
        // ---- gates = bias + x_t @ Wih^T + h_{t-1} @ Whh^T  (16x16 tile per wave) ----
        f32x4 acc = f32x4{bias_n, bias_n, bias_n, bias_n};
        for (int ks = 0; ks < 8; ks++) {
            short8 af = *(const short8*)&x_lds[(mt * 16 + l15) * XLDS_STRIDE + ks * 32 + quad * 8];
            acc = __builtin_amdgcn_mfma_f32_16x16x32_bf16(af, wih_frag[ks], acc, 0, 0, 0);
        }
        for (int ks = 0; ks < 16; ks++) {
            short8 af = *(const short8*)&h_lds[(mt * 16 + l15) * HLDS_STRIDE + ks * 32 + quad * 8];
            acc = __builtin_amdgcn_mfma_f32_16x16x32_bf16(af, whh_frag[ks], acc, 0, 0, 0);
        }
        for (int r = 0; r < 4; r++) {
            int b = mt * 16 + quad * 4 + r;
            gates_lds[(gate * 32 + b) * 16 + l15] = acc[r];
        }
        __syncthreads();

        // ---- elementwise; c lives in this thread's register ----
        {
            float iv = gates_lds[(0 * 32 + eb) * 16 + ek];
            float fv = gates_lds[(1 * 32 + eb) * 16 + ek];
            float gv = gates_lds[(2 * 32 + eb) * 16 + ek];
            float ov = gates_lds[(3 * 32 + eb) * 16 + ek];
            iv = 1.0f / (1.0f + __expf(-iv));
            fv = 1.0f / (1.0f + __expf(-fv));
            gv = tanhf(gv);
            ov = 1.0f / (1.0f + __expf(-ov));
            c = fv * c + iv * gv;
            float h = ov * tanhf(c);
            out_base[t] = h;
            __hip_atomic_store(&hbuf[(t & 1) * 16384 + eb * 512 + hidx], h,
                               __ATOMIC_RELAXED, __HIP_MEMORY_SCOPE_AGENT);
        }

        // ---- restage x_lds for t+1 (x_lds reads all done: gates sync passed) ----
        if (t + 1 < 1024) {
            const unsigned short* src = xT + (size_t)(t + 1) * 8192 + tid * 16;
            int b = tid >> 4, d = (tid & 15) * 16;
            *(short8*)&x_lds[b * XLDS_STRIDE + d]     = *(const short8*)src;
            *(short8*)&x_lds[b * XLDS_STRIDE + d + 8] = *(const short8*)(src + 8);
        }

        // ---- grid barrier (publish h_t) ----
        __builtin_amdgcn_fence(__ATOMIC_RELEASE, "agent");
        __syncthreads();
        if (tid == 0) {
            unsigned old = __hip_atomic_fetch_add(cnt, 1u, __ATOMIC_ACQ_REL, __HIP_MEMORY_SCOPE_AGENT);
            if (old == NBLK - 1) {
                __hip_atomic_store(cnt, 0u, __ATOMIC_RELAXED, __HIP_MEMORY_SCOPE_AGENT);
                __hip_atomic_fetch_add(gen, 1u, __ATOMIC_RELEASE, __HIP_MEMORY_SCOPE_AGENT);
            } else {
                while (__hip_atomic_load(gen, __ATOMIC_ACQUIRE, __HIP_MEMORY_SCOPE_AGENT) < (unsigned)(t + 1))
                    __builtin_amdgcn_s_sleep(1);
            }
        }
        __syncthreads();
        __builtin_amdgcn_fence(__ATOMIC_ACQUIRE, "agent");

        // ---- reload h_t into LDS as bf16 ----
        {
            const float* hsrc = &hbuf[(t & 1) * 16384];
            for (int i = 0; i < 32; i++) {
                int idx = i * 512 + tid;
                float hv = __hip_atomic_load(&hsrc[idx], __ATOMIC_RELAXED, __HIP_MEMORY_SCOPE_AGENT);
                int b2 = idx >> 9, k2 = idx & 511;
                h_lds[b2 * HLDS_STRIDE + k2] = f2bf(hv);
            }
        }
        __syncthreads();
    }
}

extern "C" void kernel_launch(void* const* d_in, const int* in_sizes, int n_in,
                              void* d_out, int out_size, void* d_ws, size_t ws_size,
                              hipStream_t stream) {
    (void)in_sizes; (void)n_in; (void)out_size; (void)ws_size;
    const float* x   = (const float*)d_in[0];
    const float* Wih = (const float*)d_in[1];
    const float* Whh = (const float*)d_in[2];
    const float* bih = (const float*)d_in[3];
    const float* bhh = (const float*)d_in[4];
    float* out = (float*)d_out;

    char* ws = (char*)d_ws;
    unsigned short* xT   = (unsigned short*)ws;              // 16,777,216 B
    unsigned* barrier_buf = (unsigned*)(ws + 16777216);      // 256 B
    float* hbuf          = (float*)(ws + 16777216 + 256);    // 131,072 B

    zero_barrier<<<1, 64, 0, stream>>>(barrier_buf);
    dim3 gT(16, 4, 32);   // t-tiles, d-tiles, b
    x_transpose<<<gT, 256, 0, stream>>>(x, xT);
    lstm_rec<<<NBLK, 512, 0, stream>>>(xT, Wih, Whh, bih, bhh, out, barrier_buf, hbuf);
}

// Round 3
// 8270.206 us; speedup vs baseline: 1.9358x; 1.9358x over previous
//
#include <hip/hip_runtime.h>
#include <math.h>

// B=32, D=256, T=1024, H=512, 4H=2048
// Two independent groups of 16 blocks; group owns 16 batches, block owns 32 h-cols.
// ws: [0,16MB) xT bf16 [T][B][D]; +16MB flags (8KB); then hbuf bf16 [2][2][16][512]
// ws required: ~16.2 MB

using short8 = __attribute__((ext_vector_type(8))) short;
using f32x4  = __attribute__((ext_vector_type(4))) float;

__device__ inline unsigned short f2bf(float f) {
    unsigned u = __float_as_uint(f);
    unsigned r = u + 0x7fffu + ((u >> 16) & 1u);
    return (unsigned short)(r >> 16);
}
__device__ inline float fsig(float x) {
    return __builtin_amdgcn_rcpf(1.0f + __expf(-x));
}
__device__ inline float ftanh(float x) {
    return 2.0f * __builtin_amdgcn_rcpf(1.0f + __expf(-2.0f * x)) - 1.0f;
}

__global__ void zero_flags(unsigned* p) {
    p[blockIdx.x * 256 + threadIdx.x] = 0u;
}

// ---------------- Phase 1: xT[t][b][d] = bf16(x[b][d][t]) ----------------
__global__ __launch_bounds__(256) void x_transpose(const float* __restrict__ x,
                                                   unsigned short* __restrict__ xT) {
    __shared__ unsigned short tile[64][65];
    const int tid = threadIdx.x;
    const int t0 = blockIdx.x * 64, d0 = blockIdx.y * 64, b = blockIdx.z;
    for (int p = 0; p < 16; p++) {
        int d = p * 4 + (tid >> 6);
        int t = tid & 63;
        tile[d][t] = f2bf(x[(b * 256 + d0 + d) * 1024 + t0 + t]);
    }
    __syncthreads();
    for (int p = 0; p < 16; p++) {
        int t = p * 4 + (tid >> 6);
        int d = tid & 63;
        xT[(size_t)(t0 + t) * 8192 + b * 256 + d0 + d] = tile[d][t];
    }
}

// ---------------- Phase 2: recurrence ----------------
#define HS 520   // h_lds row stride (shorts)
#define XS 264   // x_lds row stride (shorts)
#define GS 33    // gates_lds row stride (floats)

__global__ __launch_bounds__(512) void lstm_rec(const unsigned short* __restrict__ xT,
                                                const float* __restrict__ Wih,
                                                const float* __restrict__ Whh,
                                                const float* __restrict__ bih,
                                                const float* __restrict__ bhh,
                                                float* __restrict__ out,
                                                unsigned* flags,
                                                unsigned short* hbuf) {
    __shared__ __align__(16) unsigned short h_lds[16 * HS];       // 16.6 KB
    __shared__ __align__(16) unsigned short x_lds[2][16 * XS];    // 16.9 KB
    __shared__ float gates_lds[4 * 16 * GS];                      // 8.4 KB

    const int tid  = threadIdx.x;
    const int wave = tid >> 6;
    const int lane = tid & 63;
    const int quad = lane >> 4, l15 = lane & 15;
    const int group = blockIdx.x & 1;          // batch group (independent recurrences)
    const int g     = blockIdx.x >> 1;         // h-slice [32g, 32g+32)
    const int gate  = wave >> 1;
    const int csub  = (wave & 1) * 16;         // column sub-tile within block's 32 cols

    const int nrow = gate * 512 + g * 32 + csub + l15;

    // one-time weight preload into registers (B-frag: B[k=quad*8+j][n=l15])
    short8 whh_frag[16];
    for (int ks = 0; ks < 16; ks++) {
        const float* p = &Whh[(size_t)nrow * 512 + ks * 32 + quad * 8];
        short8 v;
        for (int j = 0; j < 8; j++) v[j] = (short)f2bf(p[j]);
        whh_frag[ks] = v;
    }
    short8 wih_frag[8];
    for (int ks = 0; ks < 8; ks++) {
        const float* p = &Wih[(size_t)nrow * 256 + ks * 32 + quad * 8];
        short8 v;
        for (int j = 0; j < 8; j++) v[j] = (short)f2bf(p[j]);
        wih_frag[ks] = v;
    }
    const float bias_n = bih[nrow] + bhh[nrow];

    // zero h_lds (h_{-1} = 0); fill xbuf[0] with xT[0]
    for (int i = tid; i < 16 * HS; i += 512) h_lds[i] = 0;
    {
        const unsigned short* src = xT + (size_t)(group * 16 + (tid >> 5)) * 256 + (tid & 31) * 8;
        *(short8*)&x_lds[0][(tid >> 5) * XS + (tid & 31) * 8] = *(const short8*)src;
    }

    const int eb = tid >> 5, ek = tid & 31;    // elementwise: local batch, local col
    const int hidx = g * 32 + ek;
    float c = 0.0f;
    float* out_base = out + ((size_t)(group * 16 + eb) * 512 + hidx) * 1024;
    unsigned* my_flags = flags + group * 256;           // 16 flags, 64B apart
    unsigned short* hb_base = hbuf + group * 8192;      // within [2][2][16][512]

    __syncthreads();

    // t=0 x-part (h_lds is zero so h-MFMAs add nothing but keep code uniform)
    f32x4 accA = f32x4{bias_n, bias_n, bias_n, bias_n};
    f32x4 accB = f32x4{0.f, 0.f, 0.f, 0.f};
    for (int ks = 0; ks < 8; ks += 2) {
        short8 a0 = *(const short8*)&x_lds[0][l15 * XS + ks * 32 + quad * 8];
        short8 a1 = *(const short8*)&x_lds[0][l15 * XS + (ks + 1) * 32 + quad * 8];
        accA = __builtin_amdgcn_mfma_f32_16x16x32_bf16(a0, wih_frag[ks], accA, 0, 0, 0);
        accB = __builtin_amdgcn_mfma_f32_16x16x32_bf16(a1, wih_frag[ks + 1], accB, 0, 0, 0);
    }

    for (int t = 0; t < 1024; t++) {
        // ---- h-part MFMAs (h_{t-1} from h_lds), two chains ----
        for (int ks = 0; ks < 16; ks += 2) {
            short8 a0 = *(const short8*)&h_lds[l15 * HS + ks * 32 + quad * 8];
            short8 a1 = *(const short8*)&h_lds[l15 * HS + (ks + 1) * 32 + quad * 8];
            accA = __builtin_amdgcn_mfma_f32_16x16x32_bf16(a0, whh_frag[ks], accA, 0, 0, 0);
            accB = __builtin_amdgcn_mfma_f32_16x16x32_bf16(a1, whh_frag[ks + 1], accB, 0, 0, 0);
        }
        for (int r = 0; r < 4; r++) {
            int b = quad * 4 + r;
            gates_lds[(gate * 16 + b) * GS + csub + l15] = accA[r] + accB[r];
        }

        // ---- prefetch x_{t+1} into the other LDS buffer (overlaps gates sync) ----
        if (t + 1 < 1024) {
            const unsigned short* src = xT + (size_t)(t + 1) * 8192 +
                                        (size_t)(group * 16 + eb) * 256 + ek * 8;
            *(short8*)&x_lds[(t + 1) & 1][eb * XS + ek * 8] = *(const short8*)src;
        }
        __syncthreads();

        // ---- elementwise gate math; c stays in registers ----
        float iv = gates_lds[(0 * 16 + eb) * GS + ek];
        float fv = gates_lds[(1 * 16 + eb) * GS + ek];
        float gv = gates_lds[(2 * 16 + eb) * GS + ek];
        float ov = gates_lds[(3 * 16 + eb) * GS + ek];
        iv = fsig(iv); fv = fsig(fv); gv = ftanh(gv); ov = fsig(ov);
        c = fv * c + iv * gv;
        float h = ov * ftanh(c);

        // publish h_t (bf16), release, flag
        hb_base[(t & 1) * 16384 + eb * 512 + hidx] = f2bf(h);
        __builtin_amdgcn_fence(__ATOMIC_RELEASE, "agent");
        if (tid == 0)
            __hip_atomic_store(&my_flags[g * 16], (unsigned)(t + 1),
                               __ATOMIC_RELAXED, __HIP_MEMORY_SCOPE_AGENT);
        // out store AFTER flag: completes during the spin, outside the fence path
        out_base[t] = h;

        if (t == 1023) break;

        // ---- next step's x-part while the barrier resolves ----
        accA = f32x4{bias_n, bias_n, bias_n, bias_n};
        accB = f32x4{0.f, 0.f, 0.f, 0.f};
        {
            const unsigned short* xb = x_lds[(t + 1) & 1];
            for (int ks = 0; ks < 8; ks += 2) {
                short8 a0 = *(const short8*)&xb[l15 * XS + ks * 32 + quad * 8];
                short8 a1 = *(const short8*)&xb[l15 * XS + (ks + 1) * 32 + quad * 8];
                accA = __builtin_amdgcn_mfma_f32_16x16x32_bf16(a0, wih_frag[ks], accA, 0, 0, 0);
                accB = __builtin_amdgcn_mfma_f32_16x16x32_bf16(a1, wih_frag[ks + 1], accB, 0, 0, 0);
            }
        }

        // ---- wait for all 16 producers of this group (parallel flag poll, no RMW) ----
        if (wave == 0 && lane < 16) {
            while (__hip_atomic_load(&my_flags[lane * 16], __ATOMIC_RELAXED,
                                     __HIP_MEMORY_SCOPE_AGENT) <= (unsigned)t) { }
        }
        __syncthreads();
        __builtin_amdgcn_fence(__ATOMIC_ACQUIRE, "agent");

        // ---- reload h_t into h_lds (bf16 vectors) ----
        {
            const unsigned short* src = hb_base + (t & 1) * 16384 + tid * 16;
            int b2 = tid >> 5, k2 = (tid & 31) * 16;
            *(short8*)&h_lds[b2 * HS + k2]     = *(const short8*)src;
            *(short8*)&h_lds[b2 * HS + k2 + 8] = *(const short8*)(src + 8);
        }
        __syncthreads();
    }
}

extern "C" void kernel_launch(void* const* d_in, const int* in_sizes, int n_in,
                              void* d_out, int out_size, void* d_ws, size_t ws_size,
                              hipStream_t stream) {
    (void)in_sizes; (void)n_in; (void)out_size; (void)ws_size;
    const float* x   = (const float*)d_in[0];
    const float* Wih = (const float*)d_in[1];
    const float* Whh = (const float*)d_in[2];
    const float* bih = (const float*)d_in[3];
    const float* bhh = (const float*)d_in[4];
    float* out = (float*)d_out;

    char* ws = (char*)d_ws;
    unsigned short* xT    = (unsigned short*)ws;             // 16,777,216 B
    unsigned* flags       = (unsigned*)(ws + 16777216);      // 8 KB (2 groups x 16 x 64B)
    unsigned short* hbuf  = (unsigned short*)(ws + 16777216 + 8192);  // 128 KB

    zero_flags<<<8, 256, 0, stream>>>(flags);
    dim3 gT(16, 4, 32);
    x_transpose<<<gT, 256, 0, stream>>>(x, xT);
    lstm_rec<<<32, 512, 0, stream>>>(xT, Wih, Whh, bih, bhh, out, flags, hbuf);
}

// Round 4
// 3137.046 us; speedup vs baseline: 5.1034x; 2.6363x over previous
//
#include <hip/hip_runtime.h>
#include <math.h>

// B=32, D=256, T=1024, H=512, 4H=2048
// Two independent groups of 16 blocks; group owns 16 batches, block owns 32 h-cols.
// Cross-block exchange via relaxed agent-scope atomics (LLC-coherent, no fences).
// ws: [0,16MB) xT bf16 [T][B][D]; +16MB flags (8KB); then hbuf bf16 [2 grp][2 phase][16][512]
// ws required: ~16.2 MB

using short8 = __attribute__((ext_vector_type(8))) short;
using f32x4  = __attribute__((ext_vector_type(4))) float;
using float4v = __attribute__((ext_vector_type(4))) float;

__device__ inline unsigned short f2bf(float f) {
    unsigned u = __float_as_uint(f);
    unsigned r = u + 0x7fffu + ((u >> 16) & 1u);
    return (unsigned short)(r >> 16);
}
__device__ inline float fsig(float x) {
    return __builtin_amdgcn_rcpf(1.0f + __expf(-x));
}
__device__ inline float ftanh(float x) {
    return 2.0f * __builtin_amdgcn_rcpf(1.0f + __expf(-2.0f * x)) - 1.0f;
}

__global__ void zero_flags(unsigned* p) {
    p[blockIdx.x * 256 + threadIdx.x] = 0u;
}

// ---------------- Phase 1: xT[t][b][d] = bf16(x[b][d][t]) ----------------
__global__ __launch_bounds__(256) void x_transpose(const float* __restrict__ x,
                                                   unsigned short* __restrict__ xT) {
    __shared__ unsigned short tile[64][65];
    const int tid = threadIdx.x;
    const int t0 = blockIdx.x * 64, d0 = blockIdx.y * 64, b = blockIdx.z;
    for (int p = 0; p < 16; p++) {
        int d = p * 4 + (tid >> 6);
        int t = tid & 63;
        tile[d][t] = f2bf(x[(b * 256 + d0 + d) * 1024 + t0 + t]);
    }
    __syncthreads();
    for (int p = 0; p < 16; p++) {
        int t = p * 4 + (tid >> 6);
        int d = tid & 63;
        xT[(size_t)(t0 + t) * 8192 + b * 256 + d0 + d] = tile[d][t];
    }
}

// ---------------- Phase 2: recurrence ----------------
#define HS 520   // h_lds row stride (shorts)
#define XS 264   // x_lds row stride (shorts)
#define GS 33    // gates_lds row stride (floats)
#define OS 17    // out_stage row stride (floats)

__global__ __launch_bounds__(512) void lstm_rec(const unsigned short* __restrict__ xT,
                                                const float* __restrict__ Wih,
                                                const float* __restrict__ Whh,
                                                const float* __restrict__ bih,
                                                const float* __restrict__ bhh,
                                                float* __restrict__ out,
                                                unsigned* flags,
                                                unsigned* hbuf_dw) {
    __shared__ __align__(16) unsigned short h_lds[16 * HS];       // 16.6 KB
    __shared__ __align__(16) unsigned short x_lds[2][16 * XS];    // 16.9 KB
    __shared__ float gates_lds[4 * 16 * GS];                      // 8.4 KB
    __shared__ __align__(8) unsigned short hstage[512];           // 1 KB  [16 b][32 col]
    __shared__ float out_stage[512 * OS];                         // 34.8 KB

    const int tid  = threadIdx.x;
    const int wave = tid >> 6;
    const int lane = tid & 63;
    const int quad = lane >> 4, l15 = lane & 15;
    const int group = blockIdx.x & 1;
    const int g     = blockIdx.x >> 1;         // h-slice [32g, 32g+32)
    const int gate  = wave >> 1;
    const int csub  = (wave & 1) * 16;

    const int nrow = gate * 512 + g * 32 + csub + l15;

    // one-time weight preload (B-frag: B[k=quad*8+j][n=l15])
    short8 whh_frag[16];
    for (int ks = 0; ks < 16; ks++) {
        const float* p = &Whh[(size_t)nrow * 512 + ks * 32 + quad * 8];
        short8 v;
        for (int j = 0; j < 8; j++) v[j] = (short)f2bf(p[j]);
        whh_frag[ks] = v;
    }
    short8 wih_frag[8];
    for (int ks = 0; ks < 8; ks++) {
        const float* p = &Wih[(size_t)nrow * 256 + ks * 32 + quad * 8];
        short8 v;
        for (int j = 0; j < 8; j++) v[j] = (short)f2bf(p[j]);
        wih_frag[ks] = v;
    }
    const float bias_n = bih[nrow] + bhh[nrow];

    for (int i = tid; i < 16 * HS; i += 512) h_lds[i] = 0;
    {
        const unsigned short* src = xT + (size_t)(group * 16 + (tid >> 5)) * 256 + (tid & 31) * 8;
        *(short8*)&x_lds[0][(tid >> 5) * XS + (tid & 31) * 8] = *(const short8*)src;
    }

    const int eb = tid >> 5, ek = tid & 31;    // elementwise: local batch, local col
    const int hidx = g * 32 + ek;
    float c = 0.0f;
    float* out_base = out + ((size_t)(group * 16 + eb) * 512 + hidx) * 1024;
    unsigned* my_flags = flags + group * 512;            // 16 flags, 128 B apart
    unsigned* hb_base = hbuf_dw + group * 8192;          // [2 phase][16 b][256 dw]

    __syncthreads();

    // t=0 x-part
    f32x4 accA = f32x4{bias_n, bias_n, bias_n, bias_n};
    f32x4 accB = f32x4{0.f, 0.f, 0.f, 0.f};
    for (int ks = 0; ks < 8; ks += 2) {
        short8 a0 = *(const short8*)&x_lds[0][l15 * XS + ks * 32 + quad * 8];
        short8 a1 = *(const short8*)&x_lds[0][l15 * XS + (ks + 1) * 32 + quad * 8];
        accA = __builtin_amdgcn_mfma_f32_16x16x32_bf16(a0, wih_frag[ks], accA, 0, 0, 0);
        accB = __builtin_amdgcn_mfma_f32_16x16x32_bf16(a1, wih_frag[ks + 1], accB, 0, 0, 0);
    }

    for (int t = 0; t < 1024; t++) {
        // ---- h-part MFMAs ----
        for (int ks = 0; ks < 16; ks += 2) {
            short8 a0 = *(const short8*)&h_lds[l15 * HS + ks * 32 + quad * 8];
            short8 a1 = *(const short8*)&h_lds[l15 * HS + (ks + 1) * 32 + quad * 8];
            accA = __builtin_amdgcn_mfma_f32_16x16x32_bf16(a0, whh_frag[ks], accA, 0, 0, 0);
            accB = __builtin_amdgcn_mfma_f32_16x16x32_bf16(a1, whh_frag[ks + 1], accB, 0, 0, 0);
        }
        for (int r = 0; r < 4; r++) {
            int b = quad * 4 + r;
            gates_lds[(gate * 16 + b) * GS + csub + l15] = accA[r] + accB[r];
        }

        // prefetch x_{t+1} (plain cached loads — L2 stays warm, no fences anywhere)
        if (t + 1 < 1024) {
            const unsigned short* src = xT + (size_t)(t + 1) * 8192 +
                                        (size_t)(group * 16 + eb) * 256 + ek * 8;
            *(short8*)&x_lds[(t + 1) & 1][eb * XS + ek * 8] = *(const short8*)src;
        }
        __syncthreads();

        // ---- elementwise ----
        float iv = gates_lds[(0 * 16 + eb) * GS + ek];
        float fv = gates_lds[(1 * 16 + eb) * GS + ek];
        float gv = gates_lds[(2 * 16 + eb) * GS + ek];
        float ov = gates_lds[(3 * 16 + eb) * GS + ek];
        iv = fsig(iv); fv = fsig(fv); gv = ftanh(gv); ov = fsig(ov);
        c = fv * c + iv * gv;
        float h = ov * ftanh(c);

        out_stage[tid * OS + (t & 15)] = h;
        hstage[eb * 32 + ek] = f2bf(h);
        __syncthreads();

        if (t < 1023) {
            // ---- publish h_t: packed dword atomics to LLC, drain, barrier, flag ----
            if (tid < 256) {
                unsigned v = *(const unsigned*)&hstage[tid * 2];   // [b=tid>>4][colpair=tid&15]
                int b = tid >> 4, cp = tid & 15;
                __hip_atomic_store(&hb_base[(t & 1) * 4096 + b * 256 + g * 16 + cp], v,
                                   __ATOMIC_RELAXED, __HIP_MEMORY_SCOPE_AGENT);
            }
            __builtin_amdgcn_s_waitcnt(0);   // all this wave's stores at coherence point
            __syncthreads();
            if (tid == 0)
                __hip_atomic_store(&my_flags[g * 32], (unsigned)(t + 1),
                                   __ATOMIC_RELAXED, __HIP_MEMORY_SCOPE_AGENT);
        }

        // ---- out flush every 16 steps (dense 64B lines, sits in the wait window) ----
        if ((t & 15) == 15) {
            int t0 = t & ~15;
            for (int q = 0; q < 4; q++) {
                float4v v = *(const float4v*)&out_stage[tid * OS + q * 4];
                *(float4v*)&out_base[t0 + q * 4] = v;
            }
        }

        if (t == 1023) break;

        // ---- next step's x-part while the flags resolve ----
        accA = f32x4{bias_n, bias_n, bias_n, bias_n};
        accB = f32x4{0.f, 0.f, 0.f, 0.f};
        {
            const unsigned short* xb = x_lds[(t + 1) & 1];
            for (int ks = 0; ks < 8; ks += 2) {
                short8 a0 = *(const short8*)&xb[l15 * XS + ks * 32 + quad * 8];
                short8 a1 = *(const short8*)&xb[l15 * XS + (ks + 1) * 32 + quad * 8];
                accA = __builtin_amdgcn_mfma_f32_16x16x32_bf16(a0, wih_frag[ks], accA, 0, 0, 0);
                accB = __builtin_amdgcn_mfma_f32_16x16x32_bf16(a1, wih_frag[ks + 1], accB, 0, 0, 0);
            }
        }

        // ---- wait for all 16 producers (parallel atomic polls) ----
        if (wave == 0 && lane < 16) {
            while (__hip_atomic_load(&my_flags[lane * 32], __ATOMIC_RELAXED,
                                     __HIP_MEMORY_SCOPE_AGENT) <= (unsigned)t) { }
        }
        __syncthreads();

        // ---- reload h_t via atomic 64-bit loads (LLC), write to LDS ----
        {
            const unsigned long long* src =
                (const unsigned long long*)&hb_base[(t & 1) * 4096 + eb * 256 + ek * 8];
            unsigned long long v0 = __hip_atomic_load(src + 0, __ATOMIC_RELAXED, __HIP_MEMORY_SCOPE_AGENT);
            unsigned long long v1 = __hip_atomic_load(src + 1, __ATOMIC_RELAXED, __HIP_MEMORY_SCOPE_AGENT);
            unsigned long long v2 = __hip_atomic_load(src + 2, __ATOMIC_RELAXED, __HIP_MEMORY_SCOPE_AGENT);
            unsigned long long v3 = __hip_atomic_load(src + 3, __ATOMIC_RELAXED, __HIP_MEMORY_SCOPE_AGENT);
            unsigned long long* dst = (unsigned long long*)&h_lds[eb * HS + ek * 16];
            dst[0] = v0; dst[1] = v1; dst[2] = v2; dst[3] = v3;
        }
        __syncthreads();
    }
}

extern "C" void kernel_launch(void* const* d_in, const int* in_sizes, int n_in,
                              void* d_out, int out_size, void* d_ws, size_t ws_size,
                              hipStream_t stream) {
    (void)in_sizes; (void)n_in; (void)out_size; (void)ws_size;
    const float* x   = (const float*)d_in[0];
    const float* Wih = (const float*)d_in[1];
    const float* Whh = (const float*)d_in[2];
    const float* bih = (const float*)d_in[3];
    const float* bhh = (const float*)d_in[4];
    float* out = (float*)d_out;

    char* ws = (char*)d_ws;
    unsigned short* xT = (unsigned short*)ws;                // 16,777,216 B
    unsigned* flags    = (unsigned*)(ws + 16777216);         // 8 KB (2 grp x 16 x 128B)
    unsigned* hbuf_dw  = (unsigned*)(ws + 16777216 + 8192);  // 64 KB

    zero_flags<<<8, 256, 0, stream>>>(flags);
    dim3 gT(16, 4, 32);
    x_transpose<<<gT, 256, 0, stream>>>(x, xT);
    lstm_rec<<<32, 512, 0, stream>>>(xT, Wih, Whh, bih, bhh, out, flags, hbuf_dw);
}